// Round 7
// baseline (275.127 us; speedup 1.0000x reference)
//
#include <hip/hip_runtime.h>
#include <hip/hip_bf16.h>
#include <hip/hip_fp16.h>

// B=8192, T=512, IN=1, H=20, OUT=1
#define B_TOTAL 8192
#define T_LEN   512
#define H       20
#define NBW     3      // batches per wave (3*20=60 lanes; 60-63 dummies -> row 3)
#define XSTR    520    // xs row stride in floats (520%32==8 -> conflict-free)
#define HROWU   12     // h row stride in uints (48B; 10 used = 20 halves)
#define WROWU   12     // ws weight row stride in uints (48B -> uint4-aligned rows)
#define WMATU   (H * WROWU)   // 240 uints per matrix

typedef _Float16 half2v __attribute__((ext_vector_type(2)));

// Direct, unguarded: gfx950 should have v_dot2_f32_f16 (f32 accumulate).
#define FDOT2(a, b, c) __builtin_amdgcn_fdot2((a), (b), (c), false)

__device__ __forceinline__ float fast_tanh(float x) {
    float e = __expf(x + x);
    return 1.0f - 2.0f * __builtin_amdgcn_rcpf(e + 1.0f);
}

__device__ __forceinline__ half2v h2v(unsigned int u) {
    return __builtin_bit_cast(half2v, u);
}

// Load 20 halves (10 packed pairs) from LDS: b128 + b128 + b64.
#define RDH(dst, base) \
    uint4 dst##A = ((const uint4*)(base))[0]; \
    uint4 dst##B = ((const uint4*)(base))[1]; \
    uint2 dst##C = *(const uint2*)(((const unsigned int*)(base)) + 8);

// acc0/acc1 += h . w  (10 x v_dot2_f32_f16, 2 chains); both packed-f16 uints.
#define DOTW(acc0, acc1, hv, wn) \
    acc0 = FDOT2(h2v(hv##A.x), h2v(wn##A.x), acc0); acc1 = FDOT2(h2v(hv##A.y), h2v(wn##A.y), acc1); \
    acc0 = FDOT2(h2v(hv##A.z), h2v(wn##A.z), acc0); acc1 = FDOT2(h2v(hv##A.w), h2v(wn##A.w), acc1); \
    acc0 = FDOT2(h2v(hv##B.x), h2v(wn##B.x), acc0); acc1 = FDOT2(h2v(hv##B.y), h2v(wn##B.y), acc1); \
    acc0 = FDOT2(h2v(hv##B.z), h2v(wn##B.z), acc0); acc1 = FDOT2(h2v(hv##B.w), h2v(wn##B.w), acc1); \
    acc0 = FDOT2(h2v(hv##C.x), h2v(wn##C.x), acc0); acc1 = FDOT2(h2v(hv##C.y), h2v(wn##C.y), acc1);

// One diagonal-pipeline tick: h0(s) [DO0], h1(s-1) [DO1], h2(s-2) [DO2].
// Single wave => DS in-order; all reads precede writes in program order.
#define TICK(sidx, DO0, DO1, DO2) { \
    float t0 = 0.f, t1 = 0.f, t2 = 0.f; \
    if (DO0 || DO1) { \
        RDH(h0v, &h0s[bb][0]) \
        if (DO0) { \
            float a0 = fmaf(xs[bb][(sidx)], wih0j, bias0), a0b = 0.f; \
            DOTW(a0, a0b, h0v, whh0) \
            t0 = fast_tanh(a0 + a0b); \
        } \
        if (DO1) { \
            float a1 = bias1, a1b = 0.f; \
            DOTW(a1, a1b, h0v, wih1) \
            RDH(h1v, &h1s[bb][0]) \
            DOTW(a1, a1b, h1v, whh1) \
            t1 = fast_tanh(a1 + a1b); \
            if (DO2) { \
                float a2 = bias2, a2b = 0.f; \
                DOTW(a2, a2b, h1v, wih2) \
                RDH(h2v, &h2s[bb][0]) \
                DOTW(a2, a2b, h2v, whh2) \
                t2 = fast_tanh(a2 + a2b); \
            } \
        } \
    } \
    if (!(DO1) && (DO2)) { \
        RDH(h1w, &h1s[bb][0]) \
        float a2 = bias2, a2b = 0.f; \
        DOTW(a2, a2b, h1w, wih2) \
        RDH(h2w, &h2s[bb][0]) \
        DOTW(a2, a2b, h2w, whh2) \
        t2 = fast_tanh(a2 + a2b); \
    } \
    if (DO0) ((__half*)&h0s[bb][0])[j] = (__half)t0; \
    if (DO1) ((__half*)&h1s[bb][0])[j] = (__half)t1; \
    if (DO2) ((__half*)&h2s[bb][0])[j] = (__half)t2; \
}

// ---- prologue: convert 5 HxH f32 matrices to packed-f16 rows in ws ----
__global__ void prep_w(const float* __restrict__ w_hh0, const float* __restrict__ w_ih1,
                       const float* __restrict__ w_hh1, const float* __restrict__ w_ih2,
                       const float* __restrict__ w_hh2, unsigned int* __restrict__ ws)
{
    int i = threadIdx.x;           // 0..127; first 100 = (matrix m, row r)
    if (i < 5 * H) {
        const float* src;
        int m = i / H, r = i - m * H;
        switch (m) {
            case 0: src = w_hh0; break;
            case 1: src = w_ih1; break;
            case 2: src = w_hh1; break;
            case 3: src = w_ih2; break;
            default: src = w_hh2; break;
        }
        const float* p = src + r * H;
        unsigned int* dst = ws + m * WMATU + r * WROWU;
        #pragma unroll
        for (int q = 0; q < 10; ++q) {
            unsigned short lo = __builtin_bit_cast(unsigned short, (_Float16)p[2*q]);
            unsigned short hi = __builtin_bit_cast(unsigned short, (_Float16)p[2*q+1]);
            dst[q] = (unsigned int)lo | ((unsigned int)hi << 16);
        }
        dst[10] = 0u; dst[11] = 0u;
    }
}

__global__ __launch_bounds__(64, 2) void rnn_wave(
    const float* __restrict__ x,
    const float* __restrict__ w_ih0,
    const float* __restrict__ b_ih0, const float* __restrict__ b_hh0,
    const float* __restrict__ b_ih1, const float* __restrict__ b_hh1,
    const float* __restrict__ b_ih2, const float* __restrict__ b_hh2,
    const float* __restrict__ fc_w,  const float* __restrict__ fc_b,
    const unsigned int* __restrict__ wpk,   // packed f16 weights (5 matrices)
    float* __restrict__ out)
{
    __shared__ __align__(16) float        xs[4][XSTR];
    __shared__ __align__(16) unsigned int h0s[4][HROWU];
    __shared__ __align__(16) unsigned int h1s[4][HROWU];
    __shared__ __align__(16) unsigned int h2s[4][HROWU];

    const int lane = threadIdx.x;      // block == one wave
    const int bb   = lane / H;         // 0..3 (3 = dummy lanes)
    const int j    = lane - bb * H;    // 0..19
    const int gb   = blockIdx.x * NBW + bb;

    // ---- one-time: stage x rows (coalesced float4), zero h state ----
    {
        const int gb0 = blockIdx.x * NBW;
        #pragma unroll
        for (int it = 0; it < 6; ++it) {
            int fidx = (it * 64 + lane) * 4;
            int row  = fidx >> 9;
            int col  = fidx & 511;
            int grow = gb0 + row;
            if (grow > B_TOTAL - 1) grow = B_TOTAL - 1;
            float4 v = *(const float4*)(x + (size_t)grow * T_LEN + col);
            *(float4*)&xs[row][col] = v;
        }
        for (int i = lane; i < 4 * HROWU; i += 64) {
            (&h0s[0][0])[i] = 0u;
            (&h1s[0][0])[i] = 0u;
            (&h2s[0][0])[i] = 0u;
        }
        for (int i = lane; i < XSTR; i += 64) xs[3][i] = 0.f;
    }

    // ---- per-lane weight rows: raw packed-f16 loads (no cvt -> cheap remat) ----
    const unsigned int* wrow = wpk + j * WROWU;
    uint4 whh0A = *(const uint4*)(wrow + 0*WMATU);
    uint4 whh0B = *(const uint4*)(wrow + 0*WMATU + 4);
    uint2 whh0C = *(const uint2*)(wrow + 0*WMATU + 8);
    uint4 wih1A = *(const uint4*)(wrow + 1*WMATU);
    uint4 wih1B = *(const uint4*)(wrow + 1*WMATU + 4);
    uint2 wih1C = *(const uint2*)(wrow + 1*WMATU + 8);
    uint4 whh1A = *(const uint4*)(wrow + 2*WMATU);
    uint4 whh1B = *(const uint4*)(wrow + 2*WMATU + 4);
    uint2 whh1C = *(const uint2*)(wrow + 2*WMATU + 8);
    uint4 wih2A = *(const uint4*)(wrow + 3*WMATU);
    uint4 wih2B = *(const uint4*)(wrow + 3*WMATU + 4);
    uint2 wih2C = *(const uint2*)(wrow + 3*WMATU + 8);
    uint4 whh2A = *(const uint4*)(wrow + 4*WMATU);
    uint4 whh2B = *(const uint4*)(wrow + 4*WMATU + 4);
    uint2 whh2C = *(const uint2*)(wrow + 4*WMATU + 8);

    const float wih0j = w_ih0[j];
    const float bias0 = b_ih0[j] + b_hh0[j];
    const float bias1 = b_ih1[j] + b_hh1[j];
    const float bias2 = b_ih2[j] + b_hh2[j];

    // ---- diagonal pipeline, wave-synchronous (no barriers) ----
    TICK(0, 1, 0, 0)
    TICK(1, 1, 1, 0)
    for (int s = 2; s < T_LEN; ++s) {
        TICK(s, 1, 1, 1)
    }
    TICK(512, 0, 1, 1)   // h1(511), h2(510)
    TICK(513, 0, 0, 1)   // h2(511)

    // ---- FC epilogue ----
    if (j == 0 && bb < NBW && gb < B_TOTAL) {
        float acc = fc_b[0];
        const __half* hp = (const __half*)&h2s[bb][0];
        #pragma unroll
        for (int k = 0; k < H; ++k)
            acc = fmaf((float)hp[k], fc_w[k], acc);
        out[gb] = acc;
    }
}

extern "C" void kernel_launch(void* const* d_in, const int* in_sizes, int n_in,
                              void* d_out, int out_size, void* d_ws, size_t ws_size,
                              hipStream_t stream) {
    const float* x     = (const float*)d_in[0];
    const float* w_ih0 = (const float*)d_in[1];
    const float* w_hh0 = (const float*)d_in[2];
    const float* b_ih0 = (const float*)d_in[3];
    const float* b_hh0 = (const float*)d_in[4];
    const float* w_ih1 = (const float*)d_in[5];
    const float* w_hh1 = (const float*)d_in[6];
    const float* b_ih1 = (const float*)d_in[7];
    const float* b_hh1 = (const float*)d_in[8];
    const float* w_ih2 = (const float*)d_in[9];
    const float* w_hh2 = (const float*)d_in[10];
    const float* b_ih2 = (const float*)d_in[11];
    const float* b_hh2 = (const float*)d_in[12];
    const float* fc_w  = (const float*)d_in[13];
    const float* fc_b  = (const float*)d_in[14];
    float* out = (float*)d_out;
    unsigned int* wpk = (unsigned int*)d_ws;   // needs 5*240*4 = 4800 B

    prep_w<<<1, 128, 0, stream>>>(w_hh0, w_ih1, w_hh1, w_ih2, w_hh2, wpk);

    const int nblocks = (B_TOTAL + NBW - 1) / NBW;   // 2731
    rnn_wave<<<nblocks, 64, 0, stream>>>(
        x, w_ih0, b_ih0, b_hh0, b_ih1, b_hh1, b_ih2, b_hh2,
        fc_w, fc_b, wpk, out);
}

// Round 10
// 271.355 us; speedup vs baseline: 1.0139x; 1.0139x over previous
//
#include <hip/hip_runtime.h>
#include <hip/hip_bf16.h>
#include <hip/hip_fp16.h>

// B=8192, T=512, IN=1, H=20, OUT=1
#define B_TOTAL 8192
#define T_LEN   512
#define H       20
#define NBW     3      // batches per wave (3*20=60 lanes; 60-63 dummies -> row 3)
#define XSTR    520    // xs row stride in floats (520%32==8 -> conflict-free)
#define HROWU   12     // h row stride in uints (48B; 10 used = 20 halves)
#define WROWU   12     // ws weight row stride in uints (48B -> uint4-aligned rows)
#define WMATU   (H * WROWU)   // 240 uints per matrix

typedef _Float16 half2v __attribute__((ext_vector_type(2)));

#define FDOT2(a, b, c) __builtin_amdgcn_fdot2((a), (b), (c), false)

// tanh(x) = 1 - 2/(exp2(x*2*log2e)+1) : mul, exp2, add, rcp, fma (2 trans)
__device__ __forceinline__ float fast_tanh(float x) {
    float e = __builtin_amdgcn_exp2f(x * 2.885390081777927f);
    return fmaf(-2.0f, __builtin_amdgcn_rcpf(e + 1.0f), 1.0f);
}

__device__ __forceinline__ half2v h2v(unsigned int u) {
    return __builtin_bit_cast(half2v, u);
}

// Load 20 halves (10 packed pairs) from LDS: b128 + b128 + b64.
#define RDH(dst, base) \
    uint4 dst##A = ((const uint4*)(base))[0]; \
    uint4 dst##B = ((const uint4*)(base))[1]; \
    uint2 dst##C = *(const uint2*)(((const unsigned int*)(base)) + 8);

// acc0/acc1 += h . w ; h packed pairs from RDH, w = 10 SCALAR uints wn##0..wn##9.
#define DOTW(acc0, acc1, hv, wn) \
    acc0 = FDOT2(h2v(hv##A.x), h2v(wn##0), acc0); acc1 = FDOT2(h2v(hv##A.y), h2v(wn##1), acc1); \
    acc0 = FDOT2(h2v(hv##A.z), h2v(wn##2), acc0); acc1 = FDOT2(h2v(hv##A.w), h2v(wn##3), acc1); \
    acc0 = FDOT2(h2v(hv##B.x), h2v(wn##4), acc0); acc1 = FDOT2(h2v(hv##B.y), h2v(wn##5), acc1); \
    acc0 = FDOT2(h2v(hv##B.z), h2v(wn##6), acc0); acc1 = FDOT2(h2v(hv##B.w), h2v(wn##7), acc1); \
    acc0 = FDOT2(h2v(hv##C.x), h2v(wn##8), acc0); acc1 = FDOT2(h2v(hv##C.y), h2v(wn##9), acc1);

// Declare 10 scalar uints and fill from a uint4/uint4/uint2 row load.
#define LDW(wn, base) \
    unsigned int wn##0, wn##1, wn##2, wn##3, wn##4, wn##5, wn##6, wn##7, wn##8, wn##9; \
    { uint4 _a = *(const uint4*)(base); \
      uint4 _b = *(const uint4*)((const unsigned int*)(base) + 4); \
      uint2 _c = *(const uint2*)((const unsigned int*)(base) + 8); \
      wn##0=_a.x; wn##1=_a.y; wn##2=_a.z; wn##3=_a.w; \
      wn##4=_b.x; wn##5=_b.y; wn##6=_b.z; wn##7=_b.w; \
      wn##8=_c.x; wn##9=_c.y; }

#define PIN10(wn) \
    asm volatile("" : "+v"(wn##0), "+v"(wn##1), "+v"(wn##2), "+v"(wn##3), "+v"(wn##4), \
                      "+v"(wn##5), "+v"(wn##6), "+v"(wn##7), "+v"(wn##8), "+v"(wn##9));

// One diagonal-pipeline tick: h0(s) [DO0], h1(s-1) [DO1], h2(s-2) [DO2].
// Single wave => DS in-order; all reads precede writes in program order.
#define TICK(sidx, DO0, DO1, DO2) { \
    float t0 = 0.f, t1 = 0.f, t2 = 0.f; \
    if (DO0 || DO1) { \
        RDH(h0v, &h0s[bb][0]) \
        if (DO0) { \
            float a0 = fmaf(xs[bb][(sidx)], wih0j, bias0), a0b = 0.f; \
            DOTW(a0, a0b, h0v, whh0_) \
            t0 = fast_tanh(a0 + a0b); \
        } \
        if (DO1) { \
            float a1 = bias1, a1b = 0.f; \
            DOTW(a1, a1b, h0v, wih1_) \
            RDH(h1v, &h1s[bb][0]) \
            DOTW(a1, a1b, h1v, whh1_) \
            t1 = fast_tanh(a1 + a1b); \
            if (DO2) { \
                float a2 = bias2, a2b = 0.f; \
                DOTW(a2, a2b, h1v, wih2_) \
                RDH(h2v, &h2s[bb][0]) \
                DOTW(a2, a2b, h2v, whh2_) \
                t2 = fast_tanh(a2 + a2b); \
            } \
        } \
    } \
    if (!(DO1) && (DO2)) { \
        RDH(h1w, &h1s[bb][0]) \
        float a2 = bias2, a2b = 0.f; \
        DOTW(a2, a2b, h1w, wih2_) \
        RDH(h2w, &h2s[bb][0]) \
        DOTW(a2, a2b, h2w, whh2_) \
        t2 = fast_tanh(a2 + a2b); \
    } \
    if (DO0) ((__half*)&h0s[bb][0])[j] = (__half)t0; \
    if (DO1) ((__half*)&h1s[bb][0])[j] = (__half)t1; \
    if (DO2) ((__half*)&h2s[bb][0])[j] = (__half)t2; \
}

// ---- prologue: convert 5 HxH f32 matrices to packed-f16 rows in ws ----
__global__ void prep_w(const float* __restrict__ w_hh0, const float* __restrict__ w_ih1,
                       const float* __restrict__ w_hh1, const float* __restrict__ w_ih2,
                       const float* __restrict__ w_hh2, unsigned int* __restrict__ ws)
{
    int i = threadIdx.x;           // 0..127; first 100 = (matrix m, row r)
    if (i < 5 * H) {
        const float* src;
        int m = i / H, r = i - m * H;
        switch (m) {
            case 0: src = w_hh0; break;
            case 1: src = w_ih1; break;
            case 2: src = w_hh1; break;
            case 3: src = w_ih2; break;
            default: src = w_hh2; break;
        }
        const float* p = src + r * H;
        unsigned int* dst = ws + m * WMATU + r * WROWU;
        #pragma unroll
        for (int q = 0; q < 10; ++q) {
            unsigned short lo = __builtin_bit_cast(unsigned short, (_Float16)p[2*q]);
            unsigned short hi = __builtin_bit_cast(unsigned short, (_Float16)p[2*q+1]);
            dst[q] = (unsigned int)lo | ((unsigned int)hi << 16);
        }
        dst[10] = 0u; dst[11] = 0u;
    }
}

__global__ __launch_bounds__(64, 3) void rnn_wave(
    const float* __restrict__ x,
    const float* __restrict__ w_ih0,
    const float* __restrict__ b_ih0, const float* __restrict__ b_hh0,
    const float* __restrict__ b_ih1, const float* __restrict__ b_hh1,
    const float* __restrict__ b_ih2, const float* __restrict__ b_hh2,
    const float* __restrict__ fc_w,  const float* __restrict__ fc_b,
    const unsigned int* __restrict__ wpk,   // packed f16 weights (5 matrices)
    float* __restrict__ out)
{
    __shared__ __align__(16) float        xs[4][XSTR];
    __shared__ __align__(16) unsigned int h0s[4][HROWU];
    __shared__ __align__(16) unsigned int h1s[4][HROWU];
    __shared__ __align__(16) unsigned int h2s[4][HROWU];

    const int lane = threadIdx.x;      // block == one wave
    const int bb   = lane / H;         // 0..3 (3 = dummy lanes)
    const int j    = lane - bb * H;    // 0..19
    const int gb   = blockIdx.x * NBW + bb;

    // ---- one-time: stage x rows (coalesced float4), zero h state ----
    {
        const int gb0 = blockIdx.x * NBW;
        #pragma unroll
        for (int it = 0; it < 6; ++it) {
            int fidx = (it * 64 + lane) * 4;
            int row  = fidx >> 9;
            int col  = fidx & 511;
            int grow = gb0 + row;
            if (grow > B_TOTAL - 1) grow = B_TOTAL - 1;
            float4 v = *(const float4*)(x + (size_t)grow * T_LEN + col);
            *(float4*)&xs[row][col] = v;
        }
        for (int i = lane; i < 4 * HROWU; i += 64) {
            (&h0s[0][0])[i] = 0u;
            (&h1s[0][0])[i] = 0u;
            (&h2s[0][0])[i] = 0u;
        }
        for (int i = lane; i < XSTR; i += 64) xs[3][i] = 0.f;
    }

    // ---- per-lane weight rows: packed-f16, loaded once into 50 scalars ----
    const unsigned int* wrow = wpk + j * WROWU;
    LDW(whh0_, wrow + 0*WMATU)
    LDW(wih1_, wrow + 1*WMATU)
    LDW(whh1_, wrow + 2*WMATU)
    LDW(wih2_, wrow + 3*WMATU)
    LDW(whh2_, wrow + 4*WMATU)

    const float wih0j = w_ih0[j];
    const float bias0 = b_ih0[j] + b_hh0[j];
    const float bias1 = b_ih1[j] + b_hh1[j];
    const float bias2 = b_ih2[j] + b_hh2[j];

    // ---- diagonal pipeline, wave-synchronous (no barriers) ----
    TICK(0, 1, 0, 0)
    TICK(1, 1, 1, 0)
    for (int s = 2; s < T_LEN; ++s) {
        // PIN: empty asm redefines all 50 weight words every iteration.
        // They can't be rematerialized or reloaded -> must stay resident.
        // (Spill-around-asm would show as WRITE_SIZE explosion — tripwire.)
        PIN10(whh0_)
        PIN10(wih1_)
        PIN10(whh1_)
        PIN10(wih2_)
        PIN10(whh2_)
        TICK(s, 1, 1, 1)
    }
    TICK(512, 0, 1, 1)   // h1(511), h2(510)
    TICK(513, 0, 0, 1)   // h2(511)

    // ---- FC epilogue ----
    if (j == 0 && bb < NBW && gb < B_TOTAL) {
        float acc = fc_b[0];
        const __half* hp = (const __half*)&h2s[bb][0];
        #pragma unroll
        for (int k = 0; k < H; ++k)
            acc = fmaf((float)hp[k], fc_w[k], acc);
        out[gb] = acc;
    }
}

extern "C" void kernel_launch(void* const* d_in, const int* in_sizes, int n_in,
                              void* d_out, int out_size, void* d_ws, size_t ws_size,
                              hipStream_t stream) {
    const float* x     = (const float*)d_in[0];
    const float* w_ih0 = (const float*)d_in[1];
    const float* w_hh0 = (const float*)d_in[2];
    const float* b_ih0 = (const float*)d_in[3];
    const float* b_hh0 = (const float*)d_in[4];
    const float* w_ih1 = (const float*)d_in[5];
    const float* w_hh1 = (const float*)d_in[6];
    const float* b_ih1 = (const float*)d_in[7];
    const float* b_hh1 = (const float*)d_in[8];
    const float* w_ih2 = (const float*)d_in[9];
    const float* w_hh2 = (const float*)d_in[10];
    const float* b_ih2 = (const float*)d_in[11];
    const float* b_hh2 = (const float*)d_in[12];
    const float* fc_w  = (const float*)d_in[13];
    const float* fc_b  = (const float*)d_in[14];
    float* out = (float*)d_out;
    unsigned int* wpk = (unsigned int*)d_ws;   // needs 5*240*4 = 4800 B

    prep_w<<<1, 128, 0, stream>>>(w_hh0, w_ih1, w_hh1, w_ih2, w_hh2, wpk);

    const int nblocks = (B_TOTAL + NBW - 1) / NBW;   // 2731
    rnn_wave<<<nblocks, 64, 0, stream>>>(
        x, w_ih0, b_ih0, b_hh0, b_ih1, b_hh1, b_ih2, b_hh2,
        fc_w, fc_b, wpk, out);
}